// Round 7
// baseline (865.088 us; speedup 1.0000x reference)
//
#include <hip/hip_runtime.h>
#include <math.h>

// Problem constants (fixed by the reference)
#define BB   2
#define TT   2048
#define CC   256          // DIM = HD = HV = K = V = 256, H = 1
#define BT   (BB*TT)      // 4096 rows
#define BTC  ((size_t)BT*CC)
#define LE   64           // expanded chunk length (32 timesteps x 2 heads)
#define LT   32           // timesteps per chunk
#define NCH  (TT/LT)      // 64 chunks per batch
#define TE   (2*TT)       // expanded sequence length

typedef __attribute__((address_space(1))) const float gfloat_t;
typedef __attribute__((address_space(3))) float lfloat_t;

// ---------------------------------------------------------------------------
// fp32 tiled GEMM: C[M,N] = A[M,K] @ B[K,N]
// ---------------------------------------------------------------------------
__global__ __launch_bounds__(256) void gemm_f32(
    const float* __restrict__ A, const float* __restrict__ B,
    float* __restrict__ C, int M, int N, int K)
{
    __shared__ float As[16][64];
    __shared__ float Bs[16][64];
    const int tid = threadIdx.x;
    const int tx = tid & 15;
    const int ty = tid >> 4;
    const int brow = blockIdx.x * 64;
    const int bcol = blockIdx.y * 64;

    const int ar = tid >> 2;
    const int ac = (tid & 3) * 4;
    const int bkr = tid >> 4;
    const int bc  = (tid & 15) * 4;

    float acc[4][4];
#pragma unroll
    for (int i = 0; i < 4; i++)
#pragma unroll
        for (int j = 0; j < 4; j++) acc[i][j] = 0.f;

    for (int kb = 0; kb < K; kb += 16) {
        float4 av = *(const float4*)(A + (size_t)(brow + ar) * K + kb + ac);
        As[ac + 0][ar] = av.x; As[ac + 1][ar] = av.y;
        As[ac + 2][ar] = av.z; As[ac + 3][ar] = av.w;
        float4 bv = *(const float4*)(B + (size_t)(kb + bkr) * N + bcol + bc);
        *(float4*)&Bs[bkr][bc] = bv;
        __syncthreads();
#pragma unroll
        for (int kk = 0; kk < 16; kk++) {
            float4 a4 = *(const float4*)&As[kk][ty * 4];
            float4 b4 = *(const float4*)&Bs[kk][tx * 4];
            float aa[4] = {a4.x, a4.y, a4.z, a4.w};
            float bb_[4] = {b4.x, b4.y, b4.z, b4.w};
#pragma unroll
            for (int i = 0; i < 4; i++)
#pragma unroll
                for (int j = 0; j < 4; j++) acc[i][j] += aa[i] * bb_[j];
        }
        __syncthreads();
    }
#pragma unroll
    for (int i = 0; i < 4; i++) {
        float4 o = make_float4(acc[i][0], acc[i][1], acc[i][2], acc[i][3]);
        *(float4*)(C + (size_t)(brow + ty * 4 + i) * N + bcol + tx * 4) = o;
    }
}

// Batched variant: 6 projections sharing A = x.
struct GemmBatch { const float* B[6]; float* C[6]; };
__global__ __launch_bounds__(256) void gemm_f32_batch(
    const float* __restrict__ A, GemmBatch p, int M, int N, int K)
{
    __shared__ float As[16][64];
    __shared__ float Bs[16][64];
    const float* __restrict__ B = p.B[blockIdx.z];
    float* __restrict__ C = p.C[blockIdx.z];
    const int tid = threadIdx.x;
    const int tx = tid & 15;
    const int ty = tid >> 4;
    const int brow = blockIdx.x * 64;
    const int bcol = blockIdx.y * 64;
    const int ar = tid >> 2;
    const int ac = (tid & 3) * 4;
    const int bkr = tid >> 4;
    const int bc  = (tid & 15) * 4;

    float acc[4][4];
#pragma unroll
    for (int i = 0; i < 4; i++)
#pragma unroll
        for (int j = 0; j < 4; j++) acc[i][j] = 0.f;

    for (int kb = 0; kb < K; kb += 16) {
        float4 av = *(const float4*)(A + (size_t)(brow + ar) * K + kb + ac);
        As[ac + 0][ar] = av.x; As[ac + 1][ar] = av.y;
        As[ac + 2][ar] = av.z; As[ac + 3][ar] = av.w;
        float4 bv = *(const float4*)(B + (size_t)(kb + bkr) * N + bcol + bc);
        *(float4*)&Bs[bkr][bc] = bv;
        __syncthreads();
#pragma unroll
        for (int kk = 0; kk < 16; kk++) {
            float4 a4 = *(const float4*)&As[kk][ty * 4];
            float4 b4 = *(const float4*)&Bs[kk][tx * 4];
            float aa[4] = {a4.x, a4.y, a4.z, a4.w};
            float bb_[4] = {b4.x, b4.y, b4.z, b4.w};
#pragma unroll
            for (int i = 0; i < 4; i++)
#pragma unroll
                for (int j = 0; j < 4; j++) acc[i][j] += aa[i] * bb_[j];
        }
        __syncthreads();
    }
#pragma unroll
    for (int i = 0; i < 4; i++) {
        float4 o = make_float4(acc[i][0], acc[i][1], acc[i][2], acc[i][3]);
        *(float4*)(C + (size_t)(brow + ty * 4 + i) * N + bcol + tx * 4) = o;
    }
}

// ---------------------------------------------------------------------------
// g / beta scalar projections.
// ---------------------------------------------------------------------------
__global__ __launch_bounds__(64) void proj_scalars(
    const float* __restrict__ x, const float* __restrict__ Wb,
    const float* __restrict__ Wa, const float* __restrict__ A_log,
    const float* __restrict__ dt_bias,
    float* __restrict__ g_arr, float* __restrict__ beta_arr)
{
    const int row = blockIdx.x;
    const int lane = threadIdx.x;
    float4 xv = ((const float4*)(x + (size_t)row * CC))[lane];
    float4 wa = ((const float4*)Wa)[lane];
    float4 w0 = ((const float4*)Wb)[lane];
    float4 w1 = ((const float4*)(Wb + CC))[lane];
    float da = xv.x * wa.x + xv.y * wa.y + xv.z * wa.z + xv.w * wa.w;
    float d0 = xv.x * w0.x + xv.y * w0.y + xv.z * w0.z + xv.w * w0.w;
    float d1 = xv.x * w1.x + xv.y * w1.y + xv.z * w1.z + xv.w * w1.w;
#pragma unroll
    for (int m = 1; m < 64; m <<= 1) {
        da += __shfl_xor(da, m, 64);
        d0 += __shfl_xor(d0, m, 64);
        d1 += __shfl_xor(d1, m, 64);
    }
    if (lane == 0) {
        float sp_in = da + dt_bias[0];
        float sp = (sp_in > 20.f) ? sp_in : log1pf(expf(sp_in));
        g_arr[row] = -expf(A_log[0]) * sp;
        beta_arr[row * 2 + 0] = 1.f / (1.f + expf(-d0));
        beta_arr[row * 2 + 1] = 1.f / (1.f + expf(-d1));
    }
}

// ---------------------------------------------------------------------------
// Causal conv (CONV=4) + silu + optional per-row l2norm.
// ---------------------------------------------------------------------------
__global__ __launch_bounds__(256) void conv_silu(
    const float* __restrict__ q_pre, const float* __restrict__ k_pre,
    const float* __restrict__ v_pre,
    const float* __restrict__ qw, const float* __restrict__ kw,
    const float* __restrict__ vw,
    float* __restrict__ qn, float* __restrict__ kn, float* __restrict__ vn)
{
    const int bt = blockIdx.x;
    const int s  = blockIdx.y;
    const int c  = threadIdx.x;
    const int t  = bt & (TT - 1);

    const float* pre; const float* w; float* out; bool donorm;
    if (s == 0)      { pre = q_pre;       w = qw;         out = qn + (size_t)bt * CC;            donorm = true;  }
    else if (s == 1) { pre = k_pre;       w = kw;         out = kn + ((size_t)bt * 2 + 0) * CC;  donorm = true;  }
    else if (s == 2) { pre = k_pre + BTC; w = kw + CC*4;  out = kn + ((size_t)bt * 2 + 1) * CC;  donorm = true;  }
    else if (s == 3) { pre = v_pre;       w = vw;         out = vn + ((size_t)bt * 2 + 0) * CC;  donorm = false; }
    else             { pre = v_pre + BTC; w = vw + CC*4;  out = vn + ((size_t)bt * 2 + 1) * CC;  donorm = false; }

    const float w0 = w[c * 4 + 0], w1 = w[c * 4 + 1], w2 = w[c * 4 + 2], w3 = w[c * 4 + 3];
    float acc = 0.f;
    if (t >= 3) acc += pre[(size_t)(bt - 3) * CC + c] * w0;
    if (t >= 2) acc += pre[(size_t)(bt - 2) * CC + c] * w1;
    if (t >= 1) acc += pre[(size_t)(bt - 1) * CC + c] * w2;
    acc += pre[(size_t)bt * CC + c] * w3;
    float val = acc / (1.f + expf(-acc));   // silu

    if (donorm) {
        float ss = val * val;
#pragma unroll
        for (int m = 1; m < 64; m <<= 1) ss += __shfl_xor(ss, m, 64);
        __shared__ float red[4];
        if ((c & 63) == 0) red[c >> 6] = ss;
        __syncthreads();
        float tot = red[0] + red[1] + red[2] + red[3];
        val *= rsqrtf(tot + 1e-6f);
    }
    out[c] = val;
}

// ---------------------------------------------------------------------------
// chunk_pre (unchanged math): A-matrix, forward substitution -> Wm, U_loc, Mq, meta
// ---------------------------------------------------------------------------
__global__ __launch_bounds__(256) void chunk_pre(
    const float* __restrict__ qn, const float* __restrict__ kn,
    const float* __restrict__ vn, const float* __restrict__ g_arr,
    const float* __restrict__ beta_arr,
    float* __restrict__ cWm, float* __restrict__ cUl,
    float* __restrict__ cMq, float* __restrict__ cMeta)
{
    extern __shared__ float sm[];
    float* Kl  = sm;              // [64][260]
    float* Al  = sm + 16640;      // [64][65]
    float* Cr  = sm + 20800;      // region C
    float* gcl = sm + 37440;
    float* bl  = sm + 37504;
    float* Dl  = sm + 37568;

    const int tid = threadIdx.x;
    const int ch = blockIdx.x, b = blockIdx.y;
    const size_t cb = (size_t)b * NCH + ch;
    const float* kg = kn + ((size_t)b * TE + (size_t)ch * LE) * CC;
    const float* vg = vn + ((size_t)b * TE + (size_t)ch * LE) * CC;
    const float* qg = qn + ((size_t)b * TT + (size_t)ch * LT) * CC;

    {
        const int r0 = (tid >> 6) * 16;
        const int k4 = (tid & 63) * 4;
#pragma unroll
        for (int m = 0; m < 16; m++) {
            float4 v = *(const float4*)(kg + (size_t)(r0 + m) * CC + k4);
            *(float4*)(Kl + (r0 + m) * 260 + k4) = v;
        }
    }
    if (tid < 64) {
        bl[tid] = beta_arr[(size_t)b * TE + (size_t)ch * LE + tid];
        Dl[tid] = (tid & 1) ? 0.f : g_arr[(size_t)b * TT + (size_t)ch * LT + (tid >> 1)];
    }
    __syncthreads();
    if (tid == 0) {
        float s = 0.f;
        for (int u = 0; u < 64; u++) { s += Dl[u]; gcl[u] = s; }
    }
    __syncthreads();
    if (tid < 64) Dl[tid] = expf(gcl[tid]);

    {
        const int ti = tid >> 4, tj = tid & 15;
        float4 acc[4][4];
#pragma unroll
        for (int a = 0; a < 4; a++)
#pragma unroll
            for (int c2 = 0; c2 < 4; c2++) acc[a][c2] = make_float4(0.f,0.f,0.f,0.f);
        for (int k4 = 0; k4 < 256; k4 += 4) {
            float4 av[4], bv[4];
#pragma unroll
            for (int m = 0; m < 4; m++) av[m] = *(const float4*)(Kl + (ti + 16*m)*260 + k4);
#pragma unroll
            for (int m = 0; m < 4; m++) bv[m] = *(const float4*)(Kl + (tj + 16*m)*260 + k4);
#pragma unroll
            for (int a = 0; a < 4; a++)
#pragma unroll
                for (int c2 = 0; c2 < 4; c2++) {
                    acc[a][c2].x += av[a].x * bv[c2].x;
                    acc[a][c2].y += av[a].y * bv[c2].y;
                    acc[a][c2].z += av[a].z * bv[c2].z;
                    acc[a][c2].w += av[a].w * bv[c2].w;
                }
        }
#pragma unroll
        for (int a = 0; a < 4; a++)
#pragma unroll
            for (int c2 = 0; c2 < 4; c2++) {
                int i = ti + 16*a, j = tj + 16*c2;
                float d = acc[a][c2].x + acc[a][c2].y + acc[a][c2].z + acc[a][c2].w;
                Al[i*65 + j] = (j < i) ? bl[i] * expf(gcl[i] - gcl[j]) * d : 0.f;
            }
    }
    {
        const int r0 = (tid >> 6) * 8;
        const int k4 = (tid & 63) * 4;
#pragma unroll
        for (int m = 0; m < 8; m++) {
            float4 v = *(const float4*)(qg + (size_t)(r0 + m) * CC + k4);
            *(float4*)(Cr + (r0 + m) * 260 + k4) = v;
        }
    }
    __syncthreads();
    {
        const int tr = tid >> 4, tj = tid & 15;
        float4 acc[2][4];
#pragma unroll
        for (int a = 0; a < 2; a++)
#pragma unroll
            for (int c2 = 0; c2 < 4; c2++) acc[a][c2] = make_float4(0.f,0.f,0.f,0.f);
        for (int k4 = 0; k4 < 256; k4 += 4) {
            float4 av[2], bv[4];
#pragma unroll
            for (int m = 0; m < 2; m++) av[m] = *(const float4*)(Cr + (tr + 16*m)*260 + k4);
#pragma unroll
            for (int m = 0; m < 4; m++) bv[m] = *(const float4*)(Kl + (tj + 16*m)*260 + k4);
#pragma unroll
            for (int a = 0; a < 2; a++)
#pragma unroll
                for (int c2 = 0; c2 < 4; c2++) {
                    acc[a][c2].x += av[a].x * bv[c2].x;
                    acc[a][c2].y += av[a].y * bv[c2].y;
                    acc[a][c2].z += av[a].z * bv[c2].z;
                    acc[a][c2].w += av[a].w * bv[c2].w;
                }
        }
#pragma unroll
        for (int a = 0; a < 2; a++)
#pragma unroll
            for (int c2 = 0; c2 < 4; c2++) {
                int r = tr + 16*a, j = tj + 16*c2, i = 2*r + 1;
                float d = acc[a][c2].x + acc[a][c2].y + acc[a][c2].z + acc[a][c2].w;
                cMq[(cb*32 + r)*64 + j] = (j <= i) ? d * expf(gcl[i] - gcl[j]) : 0.f;
            }
    }
    if (tid < 32)                cMeta[cb*128 + tid] = Dl[2*tid + 1];
    if (tid >= 32 && tid < 96)   cMeta[cb*128 + tid] = expf(gcl[63] - gcl[tid - 32]);
    if (tid == 96)               cMeta[cb*128 + 96]  = Dl[63];
    __syncthreads();

    float* Xs = Cr;
    for (int i = 0; i < 64; i++) Xs[i*260 + tid] = bl[i] * Dl[i] * Kl[i*260 + tid];
    for (int i = 1; i < 64; i++) {
        float a2 = Xs[i*260 + tid];
        const float* arow = Al + i*65;
        for (int j = 0; j < i; j++) a2 -= arow[j] * Xs[j*260 + tid];
        Xs[i*260 + tid] = a2;
    }
    {
        float* Wg = cWm + cb * (size_t)(LE*CC);
        for (int i = 0; i < 64; i++) Wg[(size_t)i*CC + tid] = Xs[i*260 + tid];
    }
    for (int i = 0; i < 64; i++) Xs[i*260 + tid] = bl[i] * vg[(size_t)i*CC + tid];
    for (int i = 1; i < 64; i++) {
        float a2 = Xs[i*260 + tid];
        const float* arow = Al + i*65;
        for (int j = 0; j < i; j++) a2 -= arow[j] * Xs[j*260 + tid];
        Xs[i*260 + tid] = a2;
    }
    {
        float* Ug = cUl + cb * (size_t)(LE*CC);
        for (int i = 0; i < 64; i++) Ug[(size_t)i*CC + tid] = Xs[i*260 + tid];
    }
}

// ---------------------------------------------------------------------------
// chain: raw barriers (no vmcnt drain), all global issues clustered at chunk
// top in consumption-aware order [q][Mq][meta][Ul][K][W]; K double-buffered
// in LDS via global_load_lds; W double-buffered in VGPRs.
// LDS float offsets:
#define SL_OFF    0        // S [4][272] (4 d-segments, seg stride 68)
#define XU_OFF    1088     // X^T [4][68]  (c-major)
#define XS_OFF    1360     // X scaled [256] (j-major, j*4+c)
#define META_OFF  1616     // 2 x [128]
#define MQ_OFF    1872     // 2 x [32][68]
#define KL_OFF    6224     // 2 x [64][256] linear (double buffer)
#define CHN_FLOATS 38992   // 155968 B
// ---------------------------------------------------------------------------
__device__ __forceinline__ float quad_sum(float x) {
    x += __int_as_float(__builtin_amdgcn_update_dpp(0, __float_as_int(x), 0xB1, 0xF, 0xF, false));
    x += __int_as_float(__builtin_amdgcn_update_dpp(0, __float_as_int(x), 0x4E, 0xF, 0xF, false));
    return x;
}

// raw barrier: LDS visibility only; global loads stay in flight.
#define RAW_BAR() do { \
    asm volatile("s_waitcnt lgkmcnt(0)\n\ts_barrier" ::: "memory"); \
    __builtin_amdgcn_sched_barrier(0); \
} while (0)

#define CHUNK_BODY(CH, WCUR, WNXT, ULCUR, ULNXT)                              \
{                                                                             \
    const int cur = (CH) & 1, nxt = cur ^ 1;                                  \
    const int chn = ((CH) + 1 < NCH) ? (CH) + 1 : NCH - 1;                    \
    const size_t cbn = (size_t)b * NCH + chn;                                 \
    /* ---- global issue cluster (order matters: q first, K/W last) ---- */   \
    float4 qv[8];                                                             \
    {                                                                         \
        const float* qrow = qn + ((size_t)b*TT + (size_t)(CH)*LT + rQ)*CC + k8*32; \
        _Pragma("unroll")                                                     \
        for (int m = 0; m < 8; m++) qv[m] = *(const float4*)(qrow + 4*m);     \
    }                                                                         \
    float4 mt0 = ((const float4*)(cMq + cbn*2048))[tid];                      \
    float4 mt1 = ((const float4*)(cMq + cbn*2048))[tid + 256];                \
    float mtv = (tid < 128) ? cMeta[cbn*128 + tid] : 0.f;                     \
    ULNXT = cUl[cbn*(size_t)(LE*CC) + (size_t)jW*CC + col0 + cX];             \
    {                                                                         \
        const float* kg = kn + ((size_t)b*TE + (size_t)chn*LE)*CC;            \
        const int w = tid >> 6, ln = tid & 63;                                \
        _Pragma("unroll")                                                     \
        for (int m = 0; m < 16; m++) {                                        \
            int b1k = m*4 + w;                                                \
            __builtin_amdgcn_global_load_lds(                                 \
                (gfloat_t*)(kg + b1k*256 + ln*4),                             \
                (lfloat_t*)&sm[KL_OFF + nxt*16384 + b1k*256], 16, 0, 0);      \
        }                                                                     \
    }                                                                         \
    {                                                                         \
        const float4* Wg4 = (const float4*)(cWm + cbn * (size_t)(LE*CC));     \
        _Pragma("unroll")                                                     \
        for (int i = 0; i < 16; i++) WNXT[i] = Wg4[64*jW + 16*cX + i];        \
    }                                                                         \
    /* ---- phase 1: Y = Wc . S (waits Wc regs -> drains prev-chunk K) ---- */\
    float pp0=0.f, pp1=0.f, pp2=0.f, pp3=0.f;                                 \
    _Pragma("unroll")                                                         \
    for (int i = 0; i < 16; i++) {                                            \
        float4 w = WCUR[i];                                                   \
        float4 s0 = *(const float4*)&sm[SL_OFF + 0*272 + cX*68 + 4*i];        \
        float4 s1 = *(const float4*)&sm[SL_OFF + 1*272 + cX*68 + 4*i];        \
        float4 s2 = *(const float4*)&sm[SL_OFF + 2*272 + cX*68 + 4*i];        \
        float4 s3 = *(const float4*)&sm[SL_OFF + 3*272 + cX*68 + 4*i];        \
        pp0 += w.x*s0.x + w.y*s0.y + w.z*s0.z + w.w*s0.w;                     \
        pp1 += w.x*s1.x + w.y*s1.y + w.z*s1.z + w.w*s1.w;                     \
        pp2 += w.x*s2.x + w.y*s2.y + w.z*s2.z + w.w*s2.w;                     \
        pp3 += w.x*s3.x + w.y*s3.y + w.z*s3.z + w.w*s3.w;                     \
    }                                                                         \
    pp0 = quad_sum(pp0); pp1 = quad_sum(pp1);                                 \
    pp2 = quad_sum(pp2); pp3 = quad_sum(pp3);                                 \
    {                                                                         \
        float y = (cX==0)?pp0:(cX==1)?pp1:(cX==2)?pp2:pp3;                    \
        float xval = ULCUR - y;                                               \
        sm[XU_OFF + cX*68 + jW] = xval;                                       \
        sm[XS_OFF + jW*4 + cX] = xval * sm[META_OFF + cur*128 + 32 + jW];     \
    }                                                                         \
    /* ---- QS: q . S (waits q regs only; K/W stay in flight) ---- */         \
    float qp0=0.f, qp1=0.f, qp2=0.f, qp3=0.f;                                 \
    _Pragma("unroll")                                                         \
    for (int i = 0; i < 8; i++) {                                             \
        float4 q4 = qv[i];                                                    \
        int so = (k8>>1)*68 + (k8&1)*32 + 4*i;                                \
        float4 s0 = *(const float4*)&sm[SL_OFF + 0*272 + so];                 \
        float4 s1 = *(const float4*)&sm[SL_OFF + 1*272 + so];                 \
        float4 s2 = *(const float4*)&sm[SL_OFF + 2*272 + so];                 \
        float4 s3 = *(const float4*)&sm[SL_OFF + 3*272 + so];                 \
        qp0 += q4.x*s0.x + q4.y*s0.y + q4.z*s0.z + q4.w*s0.w;                 \
        qp1 += q4.x*s1.x + q4.y*s1.y + q4.z*s1.z + q4.w*s1.w;                 \
        qp2 += q4.x*s2.x + q4.y*s2.y + q4.z*s2.z + q4.w*s2.w;                 \
        qp3 += q4.x*s3.x + q4.y*s3.y + q4.z*s3.z + q4.w*s3.w;                 \
    }                                                                         \
    qp0 = quad_sum(qp0); qp1 = quad_sum(qp1);                                 \
    qp2 = quad_sum(qp2); qp3 = quad_sum(qp3);                                 \
    float qsel = ((k8&3)==0)?qp0:((k8&3)==1)?qp1:((k8&3)==2)?qp2:qp3;         \
    float qtot = qsel + __shfl_xor(qsel, 4, 64);                              \
    RAW_BAR();  /* barrier 1: X/Xs visible; K[CH] resident (Wc-wait) */       \
    /* ---- S update: S = DL*S + K^T Xs (K from LDS buf cur) ---- */          \
    {                                                                         \
        const float DL = sm[META_OFF + cur*128 + 96];                         \
        const int seg = (tid>>6)*68 + (tid&63);                               \
        float s0 = DL * sm[SL_OFF + 0*272 + seg];                             \
        float s1 = DL * sm[SL_OFF + 1*272 + seg];                             \
        float s2 = DL * sm[SL_OFF + 2*272 + seg];                             \
        float s3 = DL * sm[SL_OFF + 3*272 + seg];                             \
        _Pragma("unroll")                                                     \
        for (int j2 = 0; j2 < 64; j2++) {                                     \
            float kv = sm[KL_OFF + cur*16384 + j2*256 + tid];                 \
            float4 xs = *(const float4*)&sm[XS_OFF + 4*j2];                   \
            s0 += kv*xs.x; s1 += kv*xs.y; s2 += kv*xs.z; s3 += kv*xs.w;       \
        }                                                                     \
        sm[SL_OFF + 0*272 + seg] = s0; sm[SL_OFF + 1*272 + seg] = s1;         \
        sm[SL_OFF + 2*272 + seg] = s2; sm[SL_OFF + 3*272 + seg] = s3;         \
    }                                                                         \
    /* ---- O finalize (lanes with k8 < 4) ---- */                            \
    if ((tid & 4) == 0) {                                                     \
        float o = sm[META_OFF + cur*128 + rQ] * qtot;                         \
        _Pragma("unroll")                                                     \
        for (int j4 = 0; j4 < 16; j4++) {                                     \
            float4 mq = *(const float4*)&sm[MQ_OFF + cur*2176 + rQ*68 + 4*j4];\
            float4 xu = *(const float4*)&sm[XU_OFF + k8*68 + 4*j4];           \
            o += mq.x*xu.x + mq.y*xu.y + mq.z*xu.z + mq.w*xu.w;               \
        }                                                                     \
        o_mid[((size_t)b*TT + (size_t)(CH)*LT + rQ)*CC + col0 + k8] = o;      \
    }                                                                         \
    /* ---- store next Mq / meta (waits mt regs; K/W newer, stay out) ---- */ \
    {                                                                         \
        int r2 = tid>>4, jj = (tid&15)*4;                                     \
        *(float4*)&sm[MQ_OFF + nxt*2176 + r2*68 + jj] = mt0;                  \
        int idx = tid + 256; r2 = idx>>4; jj = (idx&15)*4;                    \
        *(float4*)&sm[MQ_OFF + nxt*2176 + r2*68 + jj] = mt1;                  \
    }                                                                         \
    if (tid < 128) sm[META_OFF + nxt*128 + tid] = mtv;                        \
    RAW_BAR();  /* barrier 2: S updated, next Mq/meta visible */              \
}

__global__ __launch_bounds__(256, 1) void chain_kernel(
    const float* __restrict__ qn, const float* __restrict__ kn,
    const float* __restrict__ cWm, const float* __restrict__ cUl,
    const float* __restrict__ cMq, const float* __restrict__ cMeta,
    float* __restrict__ o_mid)
{
    extern __shared__ float sm[];
    const int tid = threadIdx.x;
    const int b = blockIdx.y;
    const int col0 = blockIdx.x * 4;
    const int jW = tid >> 2, cX = tid & 3;   // phase1 / X ownership
    const int rQ = tid >> 3, k8 = tid & 7;   // QS mapping

    // prologue: zero S, stage chunk 0 (W regs, Ul, Mq, meta, K[0]->LDS buf0)
    for (int p = tid; p < 1088; p += 256) sm[SL_OFF + p] = 0.f;
    float4 Wc[16], Wn[16];
    float ulc, uln;
    {
        const size_t cb0 = (size_t)b * NCH;
        const float4* Wg4 = (const float4*)(cWm + cb0 * (size_t)(LE*CC));
#pragma unroll
        for (int i = 0; i < 16; i++) Wc[i] = Wg4[64*jW + 16*cX + i];
        ulc = cUl[cb0*(size_t)(LE*CC) + (size_t)jW*CC + col0 + cX];
        float4 m0 = ((const float4*)(cMq + cb0*2048))[tid];
        float4 m1 = ((const float4*)(cMq + cb0*2048))[tid + 256];
        int r2 = tid>>4, jj = (tid&15)*4;
        *(float4*)&sm[MQ_OFF + r2*68 + jj] = m0;
        int idx = tid + 256; r2 = idx>>4; jj = (idx&15)*4;
        *(float4*)&sm[MQ_OFF + r2*68 + jj] = m1;
        if (tid < 128) sm[META_OFF + tid] = cMeta[cb0*128 + tid];
        // K[0] -> LDS buf 0
        const float* kg = kn + (size_t)b*TE*CC;
        const int w = tid >> 6, ln = tid & 63;
#pragma unroll
        for (int m = 0; m < 16; m++) {
            int b1k = m*4 + w;
            __builtin_amdgcn_global_load_lds(
                (gfloat_t*)(kg + b1k*256 + ln*4),
                (lfloat_t*)&sm[KL_OFF + 0*16384 + b1k*256], 16, 0, 0);
        }
    }
    __syncthreads();   // full drain once (prologue only)

    for (int ch = 0; ch < NCH; ch += 2) {
        CHUNK_BODY(ch,     Wc, Wn, ulc, uln);
        CHUNK_BODY(ch + 1, Wn, Wc, uln, ulc);
    }
}

// ---------------------------------------------------------------------------
// o = o * rsqrt(mean(o^2) + 1e-5) * o_norm_w * silu(gate)
// ---------------------------------------------------------------------------
__global__ __launch_bounds__(256) void norm_gate(
    const float* __restrict__ o_mid, float* __restrict__ gate,
    const float* __restrict__ onw)
{
    const int bt = blockIdx.x;
    const int c  = threadIdx.x;
    const float o = o_mid[(size_t)bt * CC + c];
    float ss = o * o;
#pragma unroll
    for (int m = 1; m < 64; m <<= 1) ss += __shfl_xor(ss, m, 64);
    __shared__ float red[4];
    if ((c & 63) == 0) red[c >> 6] = ss;
    __syncthreads();
    const float mean = (red[0] + red[1] + red[2] + red[3]) * (1.f / 256.f);
    const float scale = rsqrtf(mean + 1e-5f);
    const float gv = gate[(size_t)bt * CC + c];
    const float silu = gv / (1.f + expf(-gv));
    gate[(size_t)bt * CC + c] = o * scale * onw[c] * silu;
}

// ---------------------------------------------------------------------------
extern "C" void kernel_launch(void* const* d_in, const int* in_sizes, int n_in,
                              void* d_out, int out_size, void* d_ws, size_t ws_size,
                              hipStream_t stream)
{
    const float* x        = (const float*)d_in[0];
    const float* Wq       = (const float*)d_in[1];
    const float* Wk       = (const float*)d_in[2];
    const float* Wv       = (const float*)d_in[3];
    const float* Wb       = (const float*)d_in[4];
    const float* Wa       = (const float*)d_in[5];
    const float* A_log    = (const float*)d_in[6];
    const float* dt_bias  = (const float*)d_in[7];
    const float* q_conv_w = (const float*)d_in[8];
    const float* k_conv_w = (const float*)d_in[9];
    const float* v_conv_w = (const float*)d_in[10];
    const float* Wg       = (const float*)d_in[11];
    const float* o_norm_w = (const float*)d_in[12];
    const float* Wo       = (const float*)d_in[13];
    float* out = (float*)d_out;

    float* ws = (float*)d_ws;
    float* q_pre  = ws;                    // BTC
    float* k_pre  = ws + 1 * BTC;          // 2*BTC
    float* v_pre  = ws + 3 * BTC;          // 2*BTC
    float* gate   = ws + 5 * BTC;          // BTC
    float* qn     = ws + 6 * BTC;          // BTC
    float* kn     = ws + 7 * BTC;          // 2*BTC (expanded (b,u,c))
    float* vn     = ws + 9 * BTC;          // 2*BTC
    float* o_mid  = ws + 11 * BTC;         // BTC
    float* g_arr  = ws + 12 * BTC;         // BT
    float* beta_a = g_arr + BT;            // 2*BT
    float* cWm    = beta_a + 2 * (size_t)BT;             // 128*64*256
    float* cUl    = cWm + (size_t)BB*NCH*LE*CC;          // 128*64*256
    float* cMq    = cUl + (size_t)BB*NCH*LE*CC;          // 128*32*64
    float* cMeta  = cMq + (size_t)BB*NCH*32*64;          // 128*128

    const int PRE_LDS = 37632 * 4;        // 150528 B
    const int CHN_LDS = CHN_FLOATS * 4;   // 155968 B
    hipFuncSetAttribute(reinterpret_cast<const void*>(chunk_pre),
                        hipFuncAttributeMaxDynamicSharedMemorySize, PRE_LDS);
    hipFuncSetAttribute(reinterpret_cast<const void*>(chain_kernel),
                        hipFuncAttributeMaxDynamicSharedMemorySize, CHN_LDS);

    const dim3 gg(BT / 64, CC / 64), gb(256);
    GemmBatch gbatch;
    gbatch.B[0] = Wq;           gbatch.C[0] = q_pre;
    gbatch.B[1] = Wk;           gbatch.C[1] = k_pre;
    gbatch.B[2] = Wk + CC*CC;   gbatch.C[2] = k_pre + BTC;
    gbatch.B[3] = Wv;           gbatch.C[3] = v_pre;
    gbatch.B[4] = Wv + CC*CC;   gbatch.C[4] = v_pre + BTC;
    gbatch.B[5] = Wg;           gbatch.C[5] = gate;
    gemm_f32_batch<<<dim3(BT/64, CC/64, 6), gb, 0, stream>>>(x, gbatch, BT, CC, CC);
    proj_scalars<<<BT, 64, 0, stream>>>(x, Wb, Wa, A_log, dt_bias, g_arr, beta_a);
    conv_silu<<<dim3(BT, 5), 256, 0, stream>>>(q_pre, k_pre, v_pre,
                                               q_conv_w, k_conv_w, v_conv_w,
                                               qn, kn, vn);
    chunk_pre<<<dim3(NCH, BB), 256, PRE_LDS, stream>>>(qn, kn, vn, g_arr, beta_a,
                                                       cWm, cUl, cMq, cMeta);
    chain_kernel<<<dim3(CC/4, BB), 256, CHN_LDS, stream>>>(qn, kn, cWm, cUl, cMq, cMeta, o_mid);
    norm_gate<<<BT, 256, 0, stream>>>(o_mid, gate, o_norm_w);
    gemm_f32<<<gg, gb, 0, stream>>>(gate, Wo, out, BT, CC, CC);
}

// Round 8
// 826.484 us; speedup vs baseline: 1.0467x; 1.0467x over previous
//
#include <hip/hip_runtime.h>
#include <math.h>

// Problem constants (fixed by the reference)
#define BB   2
#define TT   2048
#define CC   256          // DIM = HD = HV = K = V = 256, H = 1
#define BT   (BB*TT)      // 4096 rows
#define BTC  ((size_t)BT*CC)
#define LE   64           // expanded chunk length (32 timesteps x 2 heads)
#define LT   32           // timesteps per chunk
#define NCH  (TT/LT)      // 64 chunks per batch
#define TE   (2*TT)       // expanded sequence length

typedef __attribute__((address_space(1))) const float gfloat_t;
typedef __attribute__((address_space(3))) float lfloat_t;

// ---------------------------------------------------------------------------
// fp32 tiled GEMM: C[M,N] = A[M,K] @ B[K,N]
// ---------------------------------------------------------------------------
__global__ __launch_bounds__(256) void gemm_f32(
    const float* __restrict__ A, const float* __restrict__ B,
    float* __restrict__ C, int M, int N, int K)
{
    __shared__ float As[16][64];
    __shared__ float Bs[16][64];
    const int tid = threadIdx.x;
    const int tx = tid & 15;
    const int ty = tid >> 4;
    const int brow = blockIdx.x * 64;
    const int bcol = blockIdx.y * 64;

    const int ar = tid >> 2;
    const int ac = (tid & 3) * 4;
    const int bkr = tid >> 4;
    const int bc  = (tid & 15) * 4;

    float acc[4][4];
#pragma unroll
    for (int i = 0; i < 4; i++)
#pragma unroll
        for (int j = 0; j < 4; j++) acc[i][j] = 0.f;

    for (int kb = 0; kb < K; kb += 16) {
        float4 av = *(const float4*)(A + (size_t)(brow + ar) * K + kb + ac);
        As[ac + 0][ar] = av.x; As[ac + 1][ar] = av.y;
        As[ac + 2][ar] = av.z; As[ac + 3][ar] = av.w;
        float4 bv = *(const float4*)(B + (size_t)(kb + bkr) * N + bcol + bc);
        *(float4*)&Bs[bkr][bc] = bv;
        __syncthreads();
#pragma unroll
        for (int kk = 0; kk < 16; kk++) {
            float4 a4 = *(const float4*)&As[kk][ty * 4];
            float4 b4 = *(const float4*)&Bs[kk][tx * 4];
            float aa[4] = {a4.x, a4.y, a4.z, a4.w};
            float bb_[4] = {b4.x, b4.y, b4.z, b4.w};
#pragma unroll
            for (int i = 0; i < 4; i++)
#pragma unroll
                for (int j = 0; j < 4; j++) acc[i][j] += aa[i] * bb_[j];
        }
        __syncthreads();
    }
#pragma unroll
    for (int i = 0; i < 4; i++) {
        float4 o = make_float4(acc[i][0], acc[i][1], acc[i][2], acc[i][3]);
        *(float4*)(C + (size_t)(brow + ty * 4 + i) * N + bcol + tx * 4) = o;
    }
}

// Batched variant: 6 projections sharing A = x.
struct GemmBatch { const float* B[6]; float* C[6]; };
__global__ __launch_bounds__(256) void gemm_f32_batch(
    const float* __restrict__ A, GemmBatch p, int M, int N, int K)
{
    __shared__ float As[16][64];
    __shared__ float Bs[16][64];
    const float* __restrict__ B = p.B[blockIdx.z];
    float* __restrict__ C = p.C[blockIdx.z];
    const int tid = threadIdx.x;
    const int tx = tid & 15;
    const int ty = tid >> 4;
    const int brow = blockIdx.x * 64;
    const int bcol = blockIdx.y * 64;
    const int ar = tid >> 2;
    const int ac = (tid & 3) * 4;
    const int bkr = tid >> 4;
    const int bc  = (tid & 15) * 4;

    float acc[4][4];
#pragma unroll
    for (int i = 0; i < 4; i++)
#pragma unroll
        for (int j = 0; j < 4; j++) acc[i][j] = 0.f;

    for (int kb = 0; kb < K; kb += 16) {
        float4 av = *(const float4*)(A + (size_t)(brow + ar) * K + kb + ac);
        As[ac + 0][ar] = av.x; As[ac + 1][ar] = av.y;
        As[ac + 2][ar] = av.z; As[ac + 3][ar] = av.w;
        float4 bv = *(const float4*)(B + (size_t)(kb + bkr) * N + bcol + bc);
        *(float4*)&Bs[bkr][bc] = bv;
        __syncthreads();
#pragma unroll
        for (int kk = 0; kk < 16; kk++) {
            float4 a4 = *(const float4*)&As[kk][ty * 4];
            float4 b4 = *(const float4*)&Bs[kk][tx * 4];
            float aa[4] = {a4.x, a4.y, a4.z, a4.w};
            float bb_[4] = {b4.x, b4.y, b4.z, b4.w};
#pragma unroll
            for (int i = 0; i < 4; i++)
#pragma unroll
                for (int j = 0; j < 4; j++) acc[i][j] += aa[i] * bb_[j];
        }
        __syncthreads();
    }
#pragma unroll
    for (int i = 0; i < 4; i++) {
        float4 o = make_float4(acc[i][0], acc[i][1], acc[i][2], acc[i][3]);
        *(float4*)(C + (size_t)(brow + ty * 4 + i) * N + bcol + tx * 4) = o;
    }
}

// ---------------------------------------------------------------------------
// g / beta scalar projections.
// ---------------------------------------------------------------------------
__global__ __launch_bounds__(64) void proj_scalars(
    const float* __restrict__ x, const float* __restrict__ Wb,
    const float* __restrict__ Wa, const float* __restrict__ A_log,
    const float* __restrict__ dt_bias,
    float* __restrict__ g_arr, float* __restrict__ beta_arr)
{
    const int row = blockIdx.x;
    const int lane = threadIdx.x;
    float4 xv = ((const float4*)(x + (size_t)row * CC))[lane];
    float4 wa = ((const float4*)Wa)[lane];
    float4 w0 = ((const float4*)Wb)[lane];
    float4 w1 = ((const float4*)(Wb + CC))[lane];
    float da = xv.x * wa.x + xv.y * wa.y + xv.z * wa.z + xv.w * wa.w;
    float d0 = xv.x * w0.x + xv.y * w0.y + xv.z * w0.z + xv.w * w0.w;
    float d1 = xv.x * w1.x + xv.y * w1.y + xv.z * w1.z + xv.w * w1.w;
#pragma unroll
    for (int m = 1; m < 64; m <<= 1) {
        da += __shfl_xor(da, m, 64);
        d0 += __shfl_xor(d0, m, 64);
        d1 += __shfl_xor(d1, m, 64);
    }
    if (lane == 0) {
        float sp_in = da + dt_bias[0];
        float sp = (sp_in > 20.f) ? sp_in : log1pf(expf(sp_in));
        g_arr[row] = -expf(A_log[0]) * sp;
        beta_arr[row * 2 + 0] = 1.f / (1.f + expf(-d0));
        beta_arr[row * 2 + 1] = 1.f / (1.f + expf(-d1));
    }
}

// ---------------------------------------------------------------------------
// Causal conv (CONV=4) + silu + optional per-row l2norm.
// ---------------------------------------------------------------------------
__global__ __launch_bounds__(256) void conv_silu(
    const float* __restrict__ q_pre, const float* __restrict__ k_pre,
    const float* __restrict__ v_pre,
    const float* __restrict__ qw, const float* __restrict__ kw,
    const float* __restrict__ vw,
    float* __restrict__ qn, float* __restrict__ kn, float* __restrict__ vn)
{
    const int bt = blockIdx.x;
    const int s  = blockIdx.y;
    const int c  = threadIdx.x;
    const int t  = bt & (TT - 1);

    const float* pre; const float* w; float* out; bool donorm;
    if (s == 0)      { pre = q_pre;       w = qw;         out = qn + (size_t)bt * CC;            donorm = true;  }
    else if (s == 1) { pre = k_pre;       w = kw;         out = kn + ((size_t)bt * 2 + 0) * CC;  donorm = true;  }
    else if (s == 2) { pre = k_pre + BTC; w = kw + CC*4;  out = kn + ((size_t)bt * 2 + 1) * CC;  donorm = true;  }
    else if (s == 3) { pre = v_pre;       w = vw;         out = vn + ((size_t)bt * 2 + 0) * CC;  donorm = false; }
    else             { pre = v_pre + BTC; w = vw + CC*4;  out = vn + ((size_t)bt * 2 + 1) * CC;  donorm = false; }

    const float w0 = w[c * 4 + 0], w1 = w[c * 4 + 1], w2 = w[c * 4 + 2], w3 = w[c * 4 + 3];
    float acc = 0.f;
    if (t >= 3) acc += pre[(size_t)(bt - 3) * CC + c] * w0;
    if (t >= 2) acc += pre[(size_t)(bt - 2) * CC + c] * w1;
    if (t >= 1) acc += pre[(size_t)(bt - 1) * CC + c] * w2;
    acc += pre[(size_t)bt * CC + c] * w3;
    float val = acc / (1.f + expf(-acc));   // silu

    if (donorm) {
        float ss = val * val;
#pragma unroll
        for (int m = 1; m < 64; m <<= 1) ss += __shfl_xor(ss, m, 64);
        __shared__ float red[4];
        if ((c & 63) == 0) red[c >> 6] = ss;
        __syncthreads();
        float tot = red[0] + red[1] + red[2] + red[3];
        val *= rsqrtf(tot + 1e-6f);
    }
    out[c] = val;
}

// ---------------------------------------------------------------------------
// chunk_pre (unchanged math): A-matrix, forward substitution -> Wm, U_loc, Mq, meta
// ---------------------------------------------------------------------------
__global__ __launch_bounds__(256) void chunk_pre(
    const float* __restrict__ qn, const float* __restrict__ kn,
    const float* __restrict__ vn, const float* __restrict__ g_arr,
    const float* __restrict__ beta_arr,
    float* __restrict__ cWm, float* __restrict__ cUl,
    float* __restrict__ cMq, float* __restrict__ cMeta)
{
    extern __shared__ float sm[];
    float* Kl  = sm;              // [64][260]
    float* Al  = sm + 16640;      // [64][65]
    float* Cr  = sm + 20800;      // region C
    float* gcl = sm + 37440;
    float* bl  = sm + 37504;
    float* Dl  = sm + 37568;

    const int tid = threadIdx.x;
    const int ch = blockIdx.x, b = blockIdx.y;
    const size_t cb = (size_t)b * NCH + ch;
    const float* kg = kn + ((size_t)b * TE + (size_t)ch * LE) * CC;
    const float* vg = vn + ((size_t)b * TE + (size_t)ch * LE) * CC;
    const float* qg = qn + ((size_t)b * TT + (size_t)ch * LT) * CC;

    {
        const int r0 = (tid >> 6) * 16;
        const int k4 = (tid & 63) * 4;
#pragma unroll
        for (int m = 0; m < 16; m++) {
            float4 v = *(const float4*)(kg + (size_t)(r0 + m) * CC + k4);
            *(float4*)(Kl + (r0 + m) * 260 + k4) = v;
        }
    }
    if (tid < 64) {
        bl[tid] = beta_arr[(size_t)b * TE + (size_t)ch * LE + tid];
        Dl[tid] = (tid & 1) ? 0.f : g_arr[(size_t)b * TT + (size_t)ch * LT + (tid >> 1)];
    }
    __syncthreads();
    if (tid == 0) {
        float s = 0.f;
        for (int u = 0; u < 64; u++) { s += Dl[u]; gcl[u] = s; }
    }
    __syncthreads();
    if (tid < 64) Dl[tid] = expf(gcl[tid]);

    {
        const int ti = tid >> 4, tj = tid & 15;
        float4 acc[4][4];
#pragma unroll
        for (int a = 0; a < 4; a++)
#pragma unroll
            for (int c2 = 0; c2 < 4; c2++) acc[a][c2] = make_float4(0.f,0.f,0.f,0.f);
        for (int k4 = 0; k4 < 256; k4 += 4) {
            float4 av[4], bv[4];
#pragma unroll
            for (int m = 0; m < 4; m++) av[m] = *(const float4*)(Kl + (ti + 16*m)*260 + k4);
#pragma unroll
            for (int m = 0; m < 4; m++) bv[m] = *(const float4*)(Kl + (tj + 16*m)*260 + k4);
#pragma unroll
            for (int a = 0; a < 4; a++)
#pragma unroll
                for (int c2 = 0; c2 < 4; c2++) {
                    acc[a][c2].x += av[a].x * bv[c2].x;
                    acc[a][c2].y += av[a].y * bv[c2].y;
                    acc[a][c2].z += av[a].z * bv[c2].z;
                    acc[a][c2].w += av[a].w * bv[c2].w;
                }
        }
#pragma unroll
        for (int a = 0; a < 4; a++)
#pragma unroll
            for (int c2 = 0; c2 < 4; c2++) {
                int i = ti + 16*a, j = tj + 16*c2;
                float d = acc[a][c2].x + acc[a][c2].y + acc[a][c2].z + acc[a][c2].w;
                Al[i*65 + j] = (j < i) ? bl[i] * expf(gcl[i] - gcl[j]) * d : 0.f;
            }
    }
    {
        const int r0 = (tid >> 6) * 8;
        const int k4 = (tid & 63) * 4;
#pragma unroll
        for (int m = 0; m < 8; m++) {
            float4 v = *(const float4*)(qg + (size_t)(r0 + m) * CC + k4);
            *(float4*)(Cr + (r0 + m) * 260 + k4) = v;
        }
    }
    __syncthreads();
    {
        const int tr = tid >> 4, tj = tid & 15;
        float4 acc[2][4];
#pragma unroll
        for (int a = 0; a < 2; a++)
#pragma unroll
            for (int c2 = 0; c2 < 4; c2++) acc[a][c2] = make_float4(0.f,0.f,0.f,0.f);
        for (int k4 = 0; k4 < 256; k4 += 4) {
            float4 av[2], bv[4];
#pragma unroll
            for (int m = 0; m < 2; m++) av[m] = *(const float4*)(Cr + (tr + 16*m)*260 + k4);
#pragma unroll
            for (int m = 0; m < 4; m++) bv[m] = *(const float4*)(Kl + (tj + 16*m)*260 + k4);
#pragma unroll
            for (int a = 0; a < 2; a++)
#pragma unroll
                for (int c2 = 0; c2 < 4; c2++) {
                    acc[a][c2].x += av[a].x * bv[c2].x;
                    acc[a][c2].y += av[a].y * bv[c2].y;
                    acc[a][c2].z += av[a].z * bv[c2].z;
                    acc[a][c2].w += av[a].w * bv[c2].w;
                }
        }
#pragma unroll
        for (int a = 0; a < 2; a++)
#pragma unroll
            for (int c2 = 0; c2 < 4; c2++) {
                int r = tr + 16*a, j = tj + 16*c2, i = 2*r + 1;
                float d = acc[a][c2].x + acc[a][c2].y + acc[a][c2].z + acc[a][c2].w;
                cMq[(cb*32 + r)*64 + j] = (j <= i) ? d * expf(gcl[i] - gcl[j]) : 0.f;
            }
    }
    if (tid < 32)                cMeta[cb*128 + tid] = Dl[2*tid + 1];
    if (tid >= 32 && tid < 96)   cMeta[cb*128 + tid] = expf(gcl[63] - gcl[tid - 32]);
    if (tid == 96)               cMeta[cb*128 + 96]  = Dl[63];
    __syncthreads();

    float* Xs = Cr;
    for (int i = 0; i < 64; i++) Xs[i*260 + tid] = bl[i] * Dl[i] * Kl[i*260 + tid];
    for (int i = 1; i < 64; i++) {
        float a2 = Xs[i*260 + tid];
        const float* arow = Al + i*65;
        for (int j = 0; j < i; j++) a2 -= arow[j] * Xs[j*260 + tid];
        Xs[i*260 + tid] = a2;
    }
    {
        float* Wg = cWm + cb * (size_t)(LE*CC);
        for (int i = 0; i < 64; i++) Wg[(size_t)i*CC + tid] = Xs[i*260 + tid];
    }
    for (int i = 0; i < 64; i++) Xs[i*260 + tid] = bl[i] * vg[(size_t)i*CC + tid];
    for (int i = 1; i < 64; i++) {
        float a2 = Xs[i*260 + tid];
        const float* arow = Al + i*65;
        for (int j = 0; j < i; j++) a2 -= arow[j] * Xs[j*260 + tid];
        Xs[i*260 + tid] = a2;
    }
    {
        float* Ug = cUl + cb * (size_t)(LE*CC);
        for (int i = 0; i < 64; i++) Ug[(size_t)i*CC + tid] = Xs[i*260 + tid];
    }
}

// ---------------------------------------------------------------------------
// chain: W in registers (double-buffered, prefetched), Q direct from global,
// K via global_load_lds (linear [64][256], conflict-free reads), DPP quad
// reductions, 2 barriers per chunk. LDS-fed loops PARTIALLY unrolled to keep
// the chunk body inside the instruction cache (R8 experiment).
// LDS float offsets:
#define SL_OFF    0        // S [4][272] (4 d-segments, seg stride 68)
#define XU_OFF    1088     // X^T [4][68]  (c-major)
#define XS_OFF    1360     // X scaled [256] (j-major, j*4+c)
#define META_OFF  1616     // 2 x [128]
#define MQ_OFF    1872     // 2 x [32][68]
#define KL_OFF    6224     // [64][256] linear
#define CHN_FLOATS 22608   // 90432 B
// ---------------------------------------------------------------------------
__device__ __forceinline__ float quad_sum(float x) {
    x += __int_as_float(__builtin_amdgcn_update_dpp(0, __float_as_int(x), 0xB1, 0xF, 0xF, false));
    x += __int_as_float(__builtin_amdgcn_update_dpp(0, __float_as_int(x), 0x4E, 0xF, 0xF, false));
    return x;
}

#define CHUNK_BODY(CH, WCUR, WNXT, ULCUR, ULNXT)                              \
{                                                                             \
    const int cur = (CH) & 1, nxt = cur ^ 1;                                  \
    const int chn = ((CH) + 1 < NCH) ? (CH) + 1 : NCH - 1;                    \
    const size_t cbn = (size_t)b * NCH + chn;                                 \
    /* async K -> LDS (consumed after barrier 1) */                           \
    {                                                                         \
        const float* kg = kn + ((size_t)b*TE + (size_t)(CH)*LE)*CC;           \
        const int w = tid >> 6, ln = tid & 63;                                \
        _Pragma("unroll")                                                     \
        for (int m = 0; m < 16; m++) {                                        \
            int b1k = m*4 + w;                                                \
            __builtin_amdgcn_global_load_lds(                                 \
                (gfloat_t*)(kg + b1k*256 + ln*4),                             \
                (lfloat_t*)&sm[KL_OFF + b1k*256], 16, 0, 0);                  \
        }                                                                     \
    }                                                                         \
    /* Q for current chunk -> regs (read-once; L2-hot) */                     \
    float4 qv[8];                                                             \
    {                                                                         \
        const float* qrow = qn + ((size_t)b*TT + (size_t)(CH)*LT + rQ)*CC + k8*32; \
        _Pragma("unroll")                                                     \
        for (int m = 0; m < 8; m++) qv[m] = *(const float4*)(qrow + 4*m);     \
    }                                                                         \
    /* phase 1: Y = W . S from registers (full unroll: reg array) */          \
    float pp0=0.f, pp1=0.f, pp2=0.f, pp3=0.f;                                 \
    _Pragma("unroll")                                                         \
    for (int i = 0; i < 16; i++) {                                            \
        float4 w = WCUR[i];                                                   \
        float4 s0 = *(const float4*)&sm[SL_OFF + 0*272 + cX*68 + 4*i];        \
        float4 s1 = *(const float4*)&sm[SL_OFF + 1*272 + cX*68 + 4*i];        \
        float4 s2 = *(const float4*)&sm[SL_OFF + 2*272 + cX*68 + 4*i];        \
        float4 s3 = *(const float4*)&sm[SL_OFF + 3*272 + cX*68 + 4*i];        \
        pp0 += w.x*s0.x + w.y*s0.y + w.z*s0.z + w.w*s0.w;                     \
        pp1 += w.x*s1.x + w.y*s1.y + w.z*s1.z + w.w*s1.w;                     \
        pp2 += w.x*s2.x + w.y*s2.y + w.z*s2.z + w.w*s2.w;                     \
        pp3 += w.x*s3.x + w.y*s3.y + w.z*s3.z + w.w*s3.w;                     \
    }                                                                         \
    pp0 = quad_sum(pp0); pp1 = quad_sum(pp1);                                 \
    pp2 = quad_sum(pp2); pp3 = quad_sum(pp3);                                 \
    {                                                                         \
        float y = (cX==0)?pp0:(cX==1)?pp1:(cX==2)?pp2:pp3;                    \
        float xval = ULCUR - y;                                               \
        sm[XU_OFF + cX*68 + jW] = xval;                                       \
        sm[XS_OFF + jW*4 + cX] = xval * sm[META_OFF + cur*128 + 32 + jW];     \
    }                                                                         \
    /* QS: q . S (full unroll: qv reg array) */                               \
    float qp0=0.f, qp1=0.f, qp2=0.f, qp3=0.f;                                 \
    _Pragma("unroll")                                                         \
    for (int i = 0; i < 8; i++) {                                             \
        float4 q4 = qv[i];                                                    \
        int so = (k8>>1)*68 + (k8&1)*32 + 4*i;                                \
        float4 s0 = *(const float4*)&sm[SL_OFF + 0*272 + so];                 \
        float4 s1 = *(const float4*)&sm[SL_OFF + 1*272 + so];                 \
        float4 s2 = *(const float4*)&sm[SL_OFF + 2*272 + so];                 \
        float4 s3 = *(const float4*)&sm[SL_OFF + 3*272 + so];                 \
        qp0 += q4.x*s0.x + q4.y*s0.y + q4.z*s0.z + q4.w*s0.w;                 \
        qp1 += q4.x*s1.x + q4.y*s1.y + q4.z*s1.z + q4.w*s1.w;                 \
        qp2 += q4.x*s2.x + q4.y*s2.y + q4.z*s2.z + q4.w*s2.w;                 \
        qp3 += q4.x*s3.x + q4.y*s3.y + q4.z*s3.z + q4.w*s3.w;                 \
    }                                                                         \
    qp0 = quad_sum(qp0); qp1 = quad_sum(qp1);                                 \
    qp2 = quad_sum(qp2); qp3 = quad_sum(qp3);                                 \
    float qsel = ((k8&3)==0)?qp0:((k8&3)==1)?qp1:((k8&3)==2)?qp2:qp3;         \
    float qtot = qsel + __shfl_xor(qsel, 4, 64);                              \
    __syncthreads();  /* barrier 1: X, Xs visible; K landed */                \
    /* prefetch next chunk (consumed after barrier 2) */                      \
    const float4* Wg4 = (const float4*)(cWm + cbn * (size_t)(LE*CC));         \
    _Pragma("unroll")                                                         \
    for (int i = 0; i < 16; i++) WNXT[i] = Wg4[64*jW + 16*cX + i];            \
    ULNXT = cUl[cbn*(size_t)(LE*CC) + (size_t)jW*CC + col0 + cX];             \
    float4 mt0 = ((const float4*)(cMq + cbn*2048))[tid];                      \
    float4 mt1 = ((const float4*)(cMq + cbn*2048))[tid + 256];                \
    float mtv = (tid < 128) ? cMeta[cbn*128 + tid] : 0.f;                     \
    /* S update: PARTIAL unroll (LDS-only indices) */                         \
    {                                                                         \
        const float DL = sm[META_OFF + cur*128 + 96];                         \
        const int seg = (tid>>6)*68 + (tid&63);                               \
        float s0 = DL * sm[SL_OFF + 0*272 + seg];                             \
        float s1 = DL * sm[SL_OFF + 1*272 + seg];                             \
        float s2 = DL * sm[SL_OFF + 2*272 + seg];                             \
        float s3 = DL * sm[SL_OFF + 3*272 + seg];                             \
        _Pragma("unroll 8")                                                   \
        for (int j2 = 0; j2 < 64; j2++) {                                     \
            float kv = sm[KL_OFF + j2*256 + tid];                             \
            float4 xs = *(const float4*)&sm[XS_OFF + 4*j2];                   \
            s0 += kv*xs.x; s1 += kv*xs.y; s2 += kv*xs.z; s3 += kv*xs.w;       \
        }                                                                     \
        sm[SL_OFF + 0*272 + seg] = s0; sm[SL_OFF + 1*272 + seg] = s1;         \
        sm[SL_OFF + 2*272 + seg] = s2; sm[SL_OFF + 3*272 + seg] = s3;         \
    }                                                                         \
    /* O finalize (lanes with k8 < 4): PARTIAL unroll */                      \
    if ((tid & 4) == 0) {                                                     \
        float o = sm[META_OFF + cur*128 + rQ] * qtot;                         \
        _Pragma("unroll 4")                                                   \
        for (int j4 = 0; j4 < 16; j4++) {                                     \
            float4 mq = *(const float4*)&sm[MQ_OFF + cur*2176 + rQ*68 + 4*j4];\
            float4 xu = *(const float4*)&sm[XU_OFF + k8*68 + 4*j4];           \
            o += mq.x*xu.x + mq.y*xu.y + mq.z*xu.z + mq.w*xu.w;               \
        }                                                                     \
        o_mid[((size_t)b*TT + (size_t)(CH)*LT + rQ)*CC + col0 + k8] = o;      \
    }                                                                         \
    /* stores of next Mq / meta */                                            \
    {                                                                         \
        int r2 = tid>>4, jj = (tid&15)*4;                                     \
        *(float4*)&sm[MQ_OFF + nxt*2176 + r2*68 + jj] = mt0;                  \
        int idx = tid + 256; r2 = idx>>4; jj = (idx&15)*4;                    \
        *(float4*)&sm[MQ_OFF + nxt*2176 + r2*68 + jj] = mt1;                  \
    }                                                                         \
    if (tid < 128) sm[META_OFF + nxt*128 + tid] = mtv;                        \
    __syncthreads();  /* barrier 2: S updated, next buffers ready */          \
}

__global__ __launch_bounds__(256, 1) void chain_kernel(
    const float* __restrict__ qn, const float* __restrict__ kn,
    const float* __restrict__ cWm, const float* __restrict__ cUl,
    const float* __restrict__ cMq, const float* __restrict__ cMeta,
    float* __restrict__ o_mid)
{
    extern __shared__ float sm[];
    const int tid = threadIdx.x;
    const int b = blockIdx.y;
    const int col0 = blockIdx.x * 4;
    const int jW = tid >> 2, cX = tid & 3;   // phase1 / X ownership
    const int rQ = tid >> 3, k8 = tid & 7;   // QS mapping

    // prologue: zero S, stage chunk 0 (W regs, Ul, Mq, meta)
    for (int p = tid; p < 1088; p += 256) sm[SL_OFF + p] = 0.f;
    float4 Wc[16], Wn[16];
    float ulc, uln;
    {
        const size_t cb0 = (size_t)b * NCH;
        const float4* Wg4 = (const float4*)(cWm + cb0 * (size_t)(LE*CC));
#pragma unroll
        for (int i = 0; i < 16; i++) Wc[i] = Wg4[64*jW + 16*cX + i];
        ulc = cUl[cb0*(size_t)(LE*CC) + (size_t)jW*CC + col0 + cX];
        float4 m0 = ((const float4*)(cMq + cb0*2048))[tid];
        float4 m1 = ((const float4*)(cMq + cb0*2048))[tid + 256];
        int r2 = tid>>4, jj = (tid&15)*4;
        *(float4*)&sm[MQ_OFF + r2*68 + jj] = m0;
        int idx = tid + 256; r2 = idx>>4; jj = (idx&15)*4;
        *(float4*)&sm[MQ_OFF + r2*68 + jj] = m1;
        if (tid < 128) sm[META_OFF + tid] = cMeta[cb0*128 + tid];
    }
    __syncthreads();

    for (int ch = 0; ch < NCH; ch += 2) {
        CHUNK_BODY(ch,     Wc, Wn, ulc, uln);
        CHUNK_BODY(ch + 1, Wn, Wc, uln, ulc);
    }
}

// ---------------------------------------------------------------------------
// o = o * rsqrt(mean(o^2) + 1e-5) * o_norm_w * silu(gate)
// ---------------------------------------------------------------------------
__global__ __launch_bounds__(256) void norm_gate(
    const float* __restrict__ o_mid, float* __restrict__ gate,
    const float* __restrict__ onw)
{
    const int bt = blockIdx.x;
    const int c  = threadIdx.x;
    const float o = o_mid[(size_t)bt * CC + c];
    float ss = o * o;
#pragma unroll
    for (int m = 1; m < 64; m <<= 1) ss += __shfl_xor(ss, m, 64);
    __shared__ float red[4];
    if ((c & 63) == 0) red[c >> 6] = ss;
    __syncthreads();
    const float mean = (red[0] + red[1] + red[2] + red[3]) * (1.f / 256.f);
    const float scale = rsqrtf(mean + 1e-5f);
    const float gv = gate[(size_t)bt * CC + c];
    const float silu = gv / (1.f + expf(-gv));
    gate[(size_t)bt * CC + c] = o * scale * onw[c] * silu;
}

// ---------------------------------------------------------------------------
extern "C" void kernel_launch(void* const* d_in, const int* in_sizes, int n_in,
                              void* d_out, int out_size, void* d_ws, size_t ws_size,
                              hipStream_t stream)
{
    const float* x        = (const float*)d_in[0];
    const float* Wq       = (const float*)d_in[1];
    const float* Wk       = (const float*)d_in[2];
    const float* Wv       = (const float*)d_in[3];
    const float* Wb       = (const float*)d_in[4];
    const float* Wa       = (const float*)d_in[5];
    const float* A_log    = (const float*)d_in[6];
    const float* dt_bias  = (const float*)d_in[7];
    const float* q_conv_w = (const float*)d_in[8];
    const float* k_conv_w = (const float*)d_in[9];
    const float* v_conv_w = (const float*)d_in[10];
    const float* Wg       = (const float*)d_in[11];
    const float* o_norm_w = (const float*)d_in[12];
    const float* Wo       = (const float*)d_in[13];
    float* out = (float*)d_out;

    float* ws = (float*)d_ws;
    float* q_pre  = ws;                    // BTC
    float* k_pre  = ws + 1 * BTC;          // 2*BTC
    float* v_pre  = ws + 3 * BTC;          // 2*BTC
    float* gate   = ws + 5 * BTC;          // BTC
    float* qn     = ws + 6 * BTC;          // BTC
    float* kn     = ws + 7 * BTC;          // 2*BTC (expanded (b,u,c))
    float* vn     = ws + 9 * BTC;          // 2*BTC
    float* o_mid  = ws + 11 * BTC;         // BTC
    float* g_arr  = ws + 12 * BTC;         // BT
    float* beta_a = g_arr + BT;            // 2*BT
    float* cWm    = beta_a + 2 * (size_t)BT;             // 128*64*256
    float* cUl    = cWm + (size_t)BB*NCH*LE*CC;          // 128*64*256
    float* cMq    = cUl + (size_t)BB*NCH*LE*CC;          // 128*32*64
    float* cMeta  = cMq + (size_t)BB*NCH*32*64;          // 128*128

    const int PRE_LDS = 37632 * 4;        // 150528 B
    const int CHN_LDS = CHN_FLOATS * 4;   // 90432 B
    hipFuncSetAttribute(reinterpret_cast<const void*>(chunk_pre),
                        hipFuncAttributeMaxDynamicSharedMemorySize, PRE_LDS);
    hipFuncSetAttribute(reinterpret_cast<const void*>(chain_kernel),
                        hipFuncAttributeMaxDynamicSharedMemorySize, CHN_LDS);

    const dim3 gg(BT / 64, CC / 64), gb(256);
    GemmBatch gbatch;
    gbatch.B[0] = Wq;           gbatch.C[0] = q_pre;
    gbatch.B[1] = Wk;           gbatch.C[1] = k_pre;
    gbatch.B[2] = Wk + CC*CC;   gbatch.C[2] = k_pre + BTC;
    gbatch.B[3] = Wv;           gbatch.C[3] = v_pre;
    gbatch.B[4] = Wv + CC*CC;   gbatch.C[4] = v_pre + BTC;
    gbatch.B[5] = Wg;           gbatch.C[5] = gate;
    gemm_f32_batch<<<dim3(BT/64, CC/64, 6), gb, 0, stream>>>(x, gbatch, BT, CC, CC);
    proj_scalars<<<BT, 64, 0, stream>>>(x, Wb, Wa, A_log, dt_bias, g_arr, beta_a);
    conv_silu<<<dim3(BT, 5), 256, 0, stream>>>(q_pre, k_pre, v_pre,
                                               q_conv_w, k_conv_w, v_conv_w,
                                               qn, kn, vn);
    chunk_pre<<<dim3(NCH, BB), 256, PRE_LDS, stream>>>(qn, kn, vn, g_arr, beta_a,
                                                       cWm, cUl, cMq, cMeta);
    chain_kernel<<<dim3(CC/4, BB), 256, CHN_LDS, stream>>>(qn, kn, cWm, cUl, cMq, cMeta, o_mid);
    norm_gate<<<BT, 256, 0, stream>>>(o_mid, gate, o_norm_w);
    gemm_f32<<<gg, gb, 0, stream>>>(gate, Wo, out, BT, CC, CC);
}